// Round 1
// baseline (1011.228 us; speedup 1.0000x reference)
//
#include <hip/hip_runtime.h>
#include <hip/hip_bf16.h>
#include <math.h>

// Problem constants
#define B_N 4096
#define BITSN 64
#define HID 512
#define EPSV 1e-5f

typedef unsigned short ushort_t;
typedef __attribute__((ext_vector_type(8))) short bf16x8;
typedef __attribute__((ext_vector_type(4))) float f32x4;

__device__ __forceinline__ ushort_t f2bf(float f) {
  unsigned u = __float_as_uint(f);
  u += 0x7FFF + ((u >> 16) & 1);   // round-to-nearest-even
  return (ushort_t)(u >> 16);
}

// ---------------- prep: bf16 copies + Wi1 position-column transpose ----------------
__global__ __launch_bounds__(256) void prep_kernel(
    const float* __restrict__ Wi2, const float* __restrict__ Wi3,
    const float* __restrict__ Wi1,
    ushort_t* __restrict__ Wi2b, ushort_t* __restrict__ Wi3b,
    float* __restrict__ Wi1posT) {
  int idx = blockIdx.x * 256 + threadIdx.x;
  if (idx < 512 * 512) Wi2b[idx] = f2bf(Wi2[idx]);
  if (idx < 64 * 512) {
    Wi3b[idx] = f2bf(Wi3[idx]);
    int p = idx >> 9, i = idx & 511;
    Wi1posT[idx] = Wi1[i * 128 + p];   // pos_part[p][i] = Wi1[i][p]
  }
}

// ---------------- shift decoder: Linear-LN-ReLU x2 -> logits -> softmax -> shift_part+bi1 ----------------
__global__ __launch_bounds__(256) void shift_kernel(
    const float* __restrict__ shift_bits,
    const float* __restrict__ W1, const float* __restrict__ b1,
    const float* __restrict__ g1, const float* __restrict__ be1,
    const float* __restrict__ W2, const float* __restrict__ b2,
    const float* __restrict__ g2, const float* __restrict__ be2,
    const float* __restrict__ W3, const float* __restrict__ b3,
    const float* __restrict__ Wi1, const float* __restrict__ bi1,
    float* __restrict__ sp) {
  __shared__ float sb[64];
  __shared__ float xv[512];
  __shared__ float hv[512];
  __shared__ float red[8];
  __shared__ float lgp[4][64];
  __shared__ float soft[64];
  int b = blockIdx.x, t = threadIdx.x;
  if (t < 64) sb[t] = shift_bits[b * 64 + t];
  __syncthreads();

  // ----- layer 1 (K=64) -----
  for (int jj = 0; jj < 2; ++jj) {
    int j = t + jj * 256;
    float acc = b1[j];
    const float4* wr = (const float4*)(W1 + j * 64);
#pragma unroll
    for (int i4 = 0; i4 < 16; ++i4) {
      float4 w = wr[i4];
      acc += w.x * sb[i4*4] + w.y * sb[i4*4+1] + w.z * sb[i4*4+2] + w.w * sb[i4*4+3];
    }
    xv[j] = acc;
  }
  __syncthreads();
  // ----- LN1 + relu -> hv -----
  {
    float a0 = xv[t], a1 = xv[t + 256];
    float s = a0 + a1, s2 = a0 * a0 + a1 * a1;
#pragma unroll
    for (int m = 32; m >= 1; m >>= 1) { s += __shfl_xor(s, m); s2 += __shfl_xor(s2, m); }
    if ((t & 63) == 0) { red[t >> 6] = s; red[4 + (t >> 6)] = s2; }
    __syncthreads();
    float S = red[0] + red[1] + red[2] + red[3];
    float S2 = red[4] + red[5] + red[6] + red[7];
    float mean = S * (1.0f / 512.0f);
    float var = S2 * (1.0f / 512.0f) - mean * mean;
    float rs = rsqrtf(var + EPSV);
    for (int jj = 0; jj < 2; ++jj) {
      int j = t + jj * 256;
      float v = (xv[j] - mean) * rs * g1[j] + be1[j];
      hv[j] = v > 0.f ? v : 0.f;
    }
  }
  __syncthreads();
  // ----- layer 2 (K=512) -----
  float o0 = 0.f, o1 = 0.f;
  for (int jj = 0; jj < 2; ++jj) {
    int j = t + jj * 256;
    float acc = b2[j];
    const float4* wr = (const float4*)(W2 + j * 512);
    const float4* hr = (const float4*)hv;
#pragma unroll 8
    for (int i4 = 0; i4 < 128; ++i4) {
      float4 w = wr[i4]; float4 h4 = hr[i4];
      acc += w.x * h4.x + w.y * h4.y + w.z * h4.z + w.w * h4.w;
    }
    if (jj == 0) o0 = acc; else o1 = acc;
  }
  __syncthreads();
  xv[t] = o0; xv[t + 256] = o1;
  __syncthreads();
  // ----- LN2 + relu -> hv -----
  {
    float a0 = xv[t], a1 = xv[t + 256];
    float s = a0 + a1, s2 = a0 * a0 + a1 * a1;
#pragma unroll
    for (int m = 32; m >= 1; m >>= 1) { s += __shfl_xor(s, m); s2 += __shfl_xor(s2, m); }
    if ((t & 63) == 0) { red[t >> 6] = s; red[4 + (t >> 6)] = s2; }
    __syncthreads();
    float S = red[0] + red[1] + red[2] + red[3];
    float S2 = red[4] + red[5] + red[6] + red[7];
    float mean = S * (1.0f / 512.0f);
    float var = S2 * (1.0f / 512.0f) - mean * mean;
    float rs = rsqrtf(var + EPSV);
    for (int jj = 0; jj < 2; ++jj) {
      int j = t + jj * 256;
      float v = (xv[j] - mean) * rs * g2[j] + be2[j];
      hv[j] = v > 0.f ? v : 0.f;
    }
  }
  __syncthreads();
  // ----- logits (64 outputs, K=512) : thread t -> (q = t>>6 quarter, p = t&63) -----
  {
    int q = t >> 6, p = t & 63;
    const float4* wr = (const float4*)(W3 + p * 512 + q * 128);
    const float4* hr = (const float4*)(hv + q * 128);
    float acc = 0.f;
#pragma unroll 8
    for (int i4 = 0; i4 < 32; ++i4) {
      float4 w = wr[i4]; float4 h4 = hr[i4];
      acc += w.x * h4.x + w.y * h4.y + w.z * h4.z + w.w * h4.w;
    }
    lgp[q][p] = acc;
  }
  __syncthreads();
  // ----- softmax over 64 logits (wave 0 only) -----
  if (t < 64) {
    float l = b3[t] + lgp[0][t] + lgp[1][t] + lgp[2][t] + lgp[3][t];
    float m = l;
#pragma unroll
    for (int mm = 32; mm >= 1; mm >>= 1) m = fmaxf(m, __shfl_xor(m, mm));
    float e = expf(l - m);
    float s = e;
#pragma unroll
    for (int mm = 32; mm >= 1; mm >>= 1) s += __shfl_xor(s, mm);
    soft[t] = e / s;
  }
  __syncthreads();
  // ----- shift_part + bi1 -> sp[b] -----
  for (int jj = 0; jj < 2; ++jj) {
    int k = t + jj * 256;
    float acc = bi1[k];
    const float4* wr = (const float4*)(Wi1 + k * 128 + 64);
#pragma unroll
    for (int i4 = 0; i4 < 16; ++i4) {
      float4 w = wr[i4];
      acc += w.x * soft[i4*4] + w.y * soft[i4*4+1] + w.z * soft[i4*4+2] + w.w * soft[i4*4+3];
    }
    sp[b * 512 + k] = acc;
  }
}

// ---------------- big fused kernel: h1 -> GEMM1(relu,bi2) -> GEMM2 -> softmax-gather ----------------
// Block = 1 batch row b, 4 waves. GEMM1: M=64 (positions) x N=512 (Wi2 rows) x K=512,
// processed in two N-halves of 256. Wave w owns n-cols [w*64, w*64+64) of each half
// (4 n-tiles) x all 4 m-tiles -> 16 acc frags. GEMM2 accumulates logits[64][64]
// across halves; wave w owns m-tile w (4 frags).
// LDS tiles XOR-swizzled on 16B granules so all ds_read_b128 are <=2-way conflicts.
__global__ __launch_bounds__(256) void big_kernel(
    const float* __restrict__ a_bits, const float* __restrict__ sp,
    const float* __restrict__ Wi1posT,
    const ushort_t* __restrict__ Wi2b, const ushort_t* __restrict__ Wi3b,
    const float* __restrict__ bi2, const float* __restrict__ bi3,
    float* __restrict__ out) {
  __shared__ __align__(16) ushort_t As[64 * 32];    // h1 k-chunk  [p][i] swizzled, 4KB
  __shared__ __align__(16) ushort_t Bs[256 * 32];   // Wi2 chunk   [c][i] swizzled, 16KB
  __shared__ __align__(16) ushort_t H2s[64 * 256];  // h2 half     [p][c] swizzled, 32KB
  __shared__ float spb[512];
  __shared__ float bi2s[512];
  __shared__ float ab[64];
  __shared__ float bi3s[64];

  int b = blockIdx.x, t = threadIdx.x;
  int w = t >> 6, l = t & 63, lg = l >> 4, l15 = l & 15;

  spb[t] = sp[b * 512 + t]; spb[t + 256] = sp[b * 512 + t + 256];
  bi2s[t] = bi2[t]; bi2s[t + 256] = bi2[t + 256];
  if (t < 64) { ab[t] = a_bits[b * 64 + t]; bi3s[t] = bi3[t]; }
  __syncthreads();

  f32x4 lacc[4];
#pragma unroll
  for (int n = 0; n < 4; ++n) lacc[n] = (f32x4){0.f, 0.f, 0.f, 0.f};

  // A-stage mapping: thread t -> row pA, granule xA; holds i-block icA = xA ^ swz(pA)
  int pA = t >> 2, xA = t & 3;
  int icA = xA ^ ((pA >> 1) & 3);
  const float* wi1row = Wi1posT + pA * 512 + icA * 8;

  for (int half = 0; half < 2; ++half) {
    int nh0 = half * 256;
    f32x4 acc[4][4];
#pragma unroll
    for (int mt = 0; mt < 4; ++mt)
#pragma unroll
      for (int nt = 0; nt < 4; ++nt) acc[mt][nt] = (f32x4){0.f, 0.f, 0.f, 0.f};

    for (int ks = 0; ks < 16; ++ks) {
      int i0 = ks * 32;
      // ---- stage A: compute h1[p][i-chunk] = relu(sp + pos), write swizzled ----
      {
        const float* spp = spb + i0 + icA * 8;
        const float* wp = wi1row + i0;
        float v[8];
#pragma unroll
        for (int j = 0; j < 8; ++j) {
          float x = spp[j] + wp[j];
          v[j] = x > 0.f ? x : 0.f;
        }
        uint4 pk;
        pk.x = (unsigned)f2bf(v[0]) | ((unsigned)f2bf(v[1]) << 16);
        pk.y = (unsigned)f2bf(v[2]) | ((unsigned)f2bf(v[3]) << 16);
        pk.z = (unsigned)f2bf(v[4]) | ((unsigned)f2bf(v[5]) << 16);
        pk.w = (unsigned)f2bf(v[6]) | ((unsigned)f2bf(v[7]) << 16);
        ((uint4*)As)[t] = pk;   // granule t = pA*4 + xA  (linear write, conflict-free)
      }
      // ---- stage B: Wi2b rows (nh0+c), i-chunk; linear dest, inverse-swizzled src ----
      {
        uint4 bq[4];
#pragma unroll
        for (int q = 0; q < 4; ++q) {
          int n = q * 256 + t;
          int c = n >> 2, xg = n & 3;
          int ic = xg ^ ((c >> 1) & 3);
          bq[q] = *(const uint4*)(Wi2b + (size_t)(nh0 + c) * 512 + i0 + ic * 8);
        }
#pragma unroll
        for (int q = 0; q < 4; ++q) ((uint4*)Bs)[q * 256 + t] = bq[q];
      }
      __syncthreads();
      // ---- compute: 16 MFMA per wave per k-step ----
      bf16x8 af[4], bfr[4];
#pragma unroll
      for (int mt = 0; mt < 4; ++mt) {
        int p = mt * 16 + l15;
        int gr = p * 4 + (lg ^ ((p >> 1) & 3));
        af[mt] = ((const bf16x8*)As)[gr];
      }
#pragma unroll
      for (int nt = 0; nt < 4; ++nt) {
        int c = w * 64 + nt * 16 + l15;
        int gr = c * 4 + (lg ^ ((c >> 1) & 3));
        bfr[nt] = ((const bf16x8*)Bs)[gr];
      }
#pragma unroll
      for (int mt = 0; mt < 4; ++mt)
#pragma unroll
        for (int nt = 0; nt < 4; ++nt)
          acc[mt][nt] = __builtin_amdgcn_mfma_f32_16x16x32_bf16(af[mt], bfr[nt], acc[mt][nt], 0, 0, 0);
      __syncthreads();
    }
    // ---- h2 = relu(acc + bi2) -> H2s (bf16, swizzled [p][c]) ----
#pragma unroll
    for (int mt = 0; mt < 4; ++mt) {
#pragma unroll
      for (int nt = 0; nt < 4; ++nt) {
        int c = w * 64 + nt * 16 + l15;
        float bi = bi2s[nh0 + c];
#pragma unroll
        for (int r = 0; r < 4; ++r) {
          int p = mt * 16 + 4 * lg + r;
          float v = acc[mt][nt][r] + bi;
          v = v > 0.f ? v : 0.f;
          H2s[p * 256 + (((c >> 3) ^ (p & 7)) * 8) + (c & 7)] = f2bf(v);
        }
      }
    }
    __syncthreads();
    // ---- GEMM2: logits[64][64] += h2_half x Wi3^T ----
    {
      int p2 = 16 * w + l15;
#pragma unroll
      for (int ks2 = 0; ks2 < 8; ++ks2) {
        int gA = (ks2 * 4 + lg) ^ (p2 & 7);
        bf16x8 a2 = *((const bf16x8*)(H2s + p2 * 256 + gA * 8));
        int k2a = nh0 + ks2 * 32 + lg * 8;
#pragma unroll
        for (int nt2 = 0; nt2 < 4; ++nt2) {
          int j2 = nt2 * 16 + l15;
          bf16x8 b2v = *((const bf16x8*)(Wi3b + (size_t)j2 * 512 + k2a));
          lacc[nt2] = __builtin_amdgcn_mfma_f32_16x16x32_bf16(a2, b2v, lacc[nt2], 0, 0, 0);
        }
      }
    }
    __syncthreads();
  }

  // ---- epilogue: per-row softmax over 64 logits + gather-sum with a_bits ----
#pragma unroll
  for (int r = 0; r < 4; ++r) {
    float v[4];
    float m = -1e30f;
#pragma unroll
    for (int nt2 = 0; nt2 < 4; ++nt2) {
      v[nt2] = lacc[nt2][r] + bi3s[nt2 * 16 + l15];
      m = fmaxf(m, v[nt2]);
    }
#pragma unroll
    for (int mm = 8; mm >= 1; mm >>= 1) m = fmaxf(m, __shfl_xor(m, mm));
    float s = 0.f, g = 0.f;
#pragma unroll
    for (int nt2 = 0; nt2 < 4; ++nt2) {
      float e = expf(v[nt2] - m);
      s += e;
      g += e * ab[nt2 * 16 + l15];
    }
#pragma unroll
    for (int mm = 8; mm >= 1; mm >>= 1) { s += __shfl_xor(s, mm); g += __shfl_xor(g, mm); }
    if (l15 == 0) out[b * 64 + 16 * w + 4 * lg + r] = g / s;
  }
}

extern "C" void kernel_launch(void* const* d_in, const int* in_sizes, int n_in,
                              void* d_out, int out_size, void* d_ws, size_t ws_size,
                              hipStream_t stream) {
  const float* a_bits     = (const float*)d_in[0];
  const float* shift_bits = (const float*)d_in[1];
  const float* W1  = (const float*)d_in[2];
  const float* b1  = (const float*)d_in[3];
  const float* g1  = (const float*)d_in[4];
  const float* be1 = (const float*)d_in[5];
  const float* W2  = (const float*)d_in[6];
  const float* b2  = (const float*)d_in[7];
  const float* g2  = (const float*)d_in[8];
  const float* be2 = (const float*)d_in[9];
  const float* W3  = (const float*)d_in[10];
  const float* b3  = (const float*)d_in[11];
  const float* Wi1 = (const float*)d_in[12];
  const float* bi1 = (const float*)d_in[13];
  const float* Wi2 = (const float*)d_in[14];
  const float* bi2 = (const float*)d_in[15];
  const float* Wi3 = (const float*)d_in[16];
  const float* bi3 = (const float*)d_in[17];
  float* out = (float*)d_out;

  // ws layout: sp fp32 [B][512] (8MB) | Wi2b bf16 [512][512] (512KB) |
  //            Wi3b bf16 [64][512] (64KB) | Wi1posT fp32 [64][512] (128KB)  => ~8.7MB
  float* sp = (float*)d_ws;
  ushort_t* Wi2b = (ushort_t*)((char*)d_ws + (size_t)B_N * HID * 4);
  ushort_t* Wi3b = Wi2b + 512 * 512;
  float* Wi1posT = (float*)(Wi3b + 64 * 512);

  prep_kernel<<<1024, 256, 0, stream>>>(Wi2, Wi3, Wi1, Wi2b, Wi3b, Wi1posT);
  shift_kernel<<<B_N, 256, 0, stream>>>(shift_bits, W1, b1, g1, be1,
                                        W2, b2, g2, be2, W3, b3, Wi1, bi1, sp);
  big_kernel<<<B_N, 256, 0, stream>>>(a_bits, sp, Wi1posT, Wi2b, Wi3b, bi2, bi3, out);
}

// Round 2
// 394.453 us; speedup vs baseline: 2.5636x; 2.5636x over previous
//
#include <hip/hip_runtime.h>
#include <hip/hip_bf16.h>
#include <math.h>

// Problem constants
#define B_N 4096
#define BITSN 64
#define HID 512
#define EPSV 1e-5f
#define BT 16   // batch rows per shift2 block

typedef unsigned short ushort_t;
typedef __attribute__((ext_vector_type(8))) short bf16x8;
typedef __attribute__((ext_vector_type(4))) float f32x4;

__device__ __forceinline__ ushort_t f2bf(float f) {
  unsigned u = __float_as_uint(f);
  u += 0x7FFF + ((u >> 16) & 1);   // round-to-nearest-even
  return (ushort_t)(u >> 16);
}

// ---------------- prep: bf16 copies + transposes ----------------
__global__ __launch_bounds__(256) void prep_kernel(
    const float* __restrict__ Wi2, const float* __restrict__ Wi3,
    const float* __restrict__ Wi1, const float* __restrict__ W1,
    const float* __restrict__ W2, const float* __restrict__ W3,
    ushort_t* __restrict__ Wi2b, ushort_t* __restrict__ Wi3b,
    float* __restrict__ Wi1posT, ushort_t* __restrict__ W1b,
    ushort_t* __restrict__ W2b, ushort_t* __restrict__ W3b,
    ushort_t* __restrict__ Wi1sb) {
  int idx = blockIdx.x * 256 + threadIdx.x;
  if (idx < 512 * 512) {
    Wi2b[idx] = f2bf(Wi2[idx]);
    W2b[idx] = f2bf(W2[idx]);
  }
  if (idx < 64 * 512) {
    Wi3b[idx] = f2bf(Wi3[idx]);
    W3b[idx] = f2bf(W3[idx]);
    int p = idx >> 9, i = idx & 511;
    Wi1posT[idx] = Wi1[i * 128 + p];   // pos_part[p][i] = Wi1[i][p]
  }
  if (idx < 512 * 64) {
    W1b[idx] = f2bf(W1[idx]);                       // [512][64]
    int j = idx >> 6, k = idx & 63;
    Wi1sb[idx] = f2bf(Wi1[j * 128 + 64 + k]);       // shift cols of Wi1: [512][64]
  }
}

// ---------------- shift decoder, MFMA-batched: 16 rows/block ----------------
// All LDS tiles row-XOR-swizzled: byte ^= ((row&7)<<4) so ds_read_b128 is <=2-way.
__global__ __launch_bounds__(256) void shift2_kernel(
    const float* __restrict__ shift_bits,
    const ushort_t* __restrict__ W1b, const float* __restrict__ b1,
    const float* __restrict__ g1, const float* __restrict__ be1,
    const ushort_t* __restrict__ W2b, const float* __restrict__ b2,
    const float* __restrict__ g2, const float* __restrict__ be2,
    const ushort_t* __restrict__ W3b, const float* __restrict__ b3,
    const ushort_t* __restrict__ Wi1sb, const float* __restrict__ bi1,
    float* __restrict__ sp) {
  __shared__ __align__(16) ushort_t hA[BT * 512];     // 16KB: h1 (post LN1+relu)
  __shared__ __align__(16) char reg2[32 * 1024];      // phase union
  __shared__ float b1s[512], g1s[512], be1s[512];
  __shared__ float b2s[512], g2s[512], be2s[512], bi1s[512];
  __shared__ float red[4][BT][2];
  __shared__ float b3s[64];

  ushort_t* sbt = (ushort_t*)reg2;                    // phase 1: shift_bits tile [16][64]
  ushort_t* Bs  = (ushort_t*)reg2;                    // phase 2: W2 tile [512][32]
  ushort_t* h2  = (ushort_t*)reg2;                    // phase 3: h2 [16][512]
  float (*lg32)[68] = (float(*)[68])(reg2 + 16 * 1024);
  ushort_t* sb2 = (ushort_t*)(reg2 + 16 * 1024 + 16 * 68 * 4);  // soft [16][64]

  int b0 = blockIdx.x * BT;
  int t = threadIdx.x, w = t >> 6, l = t & 63, lg = l >> 4, l15 = l & 15;

  b1s[t] = b1[t];  b1s[t + 256] = b1[t + 256];
  g1s[t] = g1[t];  g1s[t + 256] = g1[t + 256];
  be1s[t] = be1[t]; be1s[t + 256] = be1[t + 256];
  b2s[t] = b2[t];  b2s[t + 256] = b2[t + 256];
  g2s[t] = g2[t];  g2s[t + 256] = g2[t + 256];
  be2s[t] = be2[t]; be2s[t + 256] = be2[t + 256];
  bi1s[t] = bi1[t]; bi1s[t + 256] = bi1[t + 256];
  if (t < 64) b3s[t] = b3[t];
  if (t < 128) {   // stage shift_bits tile -> bf16 swizzled
    int row = t >> 3, g = t & 7;
    const float* src = shift_bits + (size_t)(b0 + row) * 64 + g * 8;
    uint4 pk;
    pk.x = (unsigned)f2bf(src[0]) | ((unsigned)f2bf(src[1]) << 16);
    pk.y = (unsigned)f2bf(src[2]) | ((unsigned)f2bf(src[3]) << 16);
    pk.z = (unsigned)f2bf(src[4]) | ((unsigned)f2bf(src[5]) << 16);
    pk.w = (unsigned)f2bf(src[6]) | ((unsigned)f2bf(src[7]) << 16);
    *(uint4*)((char*)sbt + ((row * 128 + g * 16) ^ ((row & 7) << 4))) = pk;
  }
  __syncthreads();

  // ----- GEMM1: x1[16][512] = sbt @ W1^T ; wave w owns cols [w*128, w*128+128) -----
  f32x4 acc[8];
#pragma unroll
  for (int nt = 0; nt < 8; ++nt) acc[nt] = (f32x4){0.f, 0.f, 0.f, 0.f};
#pragma unroll
  for (int ks = 0; ks < 2; ++ks) {
    bf16x8 af = *(const bf16x8*)((char*)sbt + ((l15 * 128 + ks * 64 + lg * 16) ^ ((l15 & 7) << 4)));
#pragma unroll
    for (int nt = 0; nt < 8; ++nt) {
      int c = w * 128 + nt * 16 + l15;
      bf16x8 bfr = *(const bf16x8*)(W1b + (size_t)c * 64 + ks * 32 + lg * 8);
      acc[nt] = __builtin_amdgcn_mfma_f32_16x16x32_bf16(af, bfr, acc[nt], 0, 0, 0);
    }
  }
  // ----- LN1 + relu -> hA -----
  {
    float s[4] = {0.f, 0.f, 0.f, 0.f}, q[4] = {0.f, 0.f, 0.f, 0.f};
#pragma unroll
    for (int nt = 0; nt < 8; ++nt) {
      int c = w * 128 + nt * 16 + l15;
      float bb = b1s[c];
#pragma unroll
      for (int r = 0; r < 4; ++r) {
        float x = acc[nt][r] + bb;
        acc[nt][r] = x;
        s[r] += x; q[r] += x * x;
      }
    }
#pragma unroll
    for (int m = 8; m >= 1; m >>= 1)
#pragma unroll
      for (int r = 0; r < 4; ++r) { s[r] += __shfl_xor(s[r], m); q[r] += __shfl_xor(q[r], m); }
    if (l15 == 0)
#pragma unroll
      for (int r = 0; r < 4; ++r) { red[w][4 * lg + r][0] = s[r]; red[w][4 * lg + r][1] = q[r]; }
    __syncthreads();
    float mean[4], rs[4];
#pragma unroll
    for (int r = 0; r < 4; ++r) {
      int p = 4 * lg + r;
      float S = red[0][p][0] + red[1][p][0] + red[2][p][0] + red[3][p][0];
      float Q = red[0][p][1] + red[1][p][1] + red[2][p][1] + red[3][p][1];
      mean[r] = S * (1.0f / 512.0f);
      float var = Q * (1.0f / 512.0f) - mean[r] * mean[r];
      rs[r] = rsqrtf(var + EPSV);
    }
#pragma unroll
    for (int nt = 0; nt < 8; ++nt) {
      int c = w * 128 + nt * 16 + l15;
      float gg = g1s[c], bb = be1s[c];
#pragma unroll
      for (int r = 0; r < 4; ++r) {
        int p = 4 * lg + r;
        float v = (acc[nt][r] - mean[r]) * rs[r] * gg + bb;
        v = v > 0.f ? v : 0.f;
        *(ushort_t*)((char*)hA + ((p * 1024 + c * 2) ^ ((p & 7) << 4))) = f2bf(v);
      }
    }
  }
  __syncthreads();

  // ----- GEMM2: x2[16][512] = hA @ W2^T, K=512 staged in 16 chunks of 32 -----
#pragma unroll
  for (int nt = 0; nt < 8; ++nt) acc[nt] = (f32x4){0.f, 0.f, 0.f, 0.f};
  for (int step = 0; step < 16; ++step) {
    int i0 = step * 32;
#pragma unroll
    for (int qq = 0; qq < 8; ++qq) {   // stage Bs [512][32] swizzled (linear writes)
      int g = qq * 256 + t;
      int c = g >> 2, xg = g & 3;
      int ic = xg ^ ((c >> 1) & 3);
      ((uint4*)Bs)[g] = *(const uint4*)(W2b + (size_t)c * 512 + i0 + ic * 8);
    }
    __syncthreads();
    bf16x8 af = *(const bf16x8*)((char*)hA + ((l15 * 1024 + step * 64 + lg * 16) ^ ((l15 & 7) << 4)));
#pragma unroll
    for (int nt = 0; nt < 8; ++nt) {
      int c = w * 128 + nt * 16 + l15;
      bf16x8 bfr = ((const bf16x8*)Bs)[c * 4 + (lg ^ ((c >> 1) & 3))];
      acc[nt] = __builtin_amdgcn_mfma_f32_16x16x32_bf16(af, bfr, acc[nt], 0, 0, 0);
    }
    __syncthreads();
  }
  // ----- LN2 + relu -> h2 (overwrites Bs region; safe: barrier above) -----
  {
    float s[4] = {0.f, 0.f, 0.f, 0.f}, q[4] = {0.f, 0.f, 0.f, 0.f};
#pragma unroll
    for (int nt = 0; nt < 8; ++nt) {
      int c = w * 128 + nt * 16 + l15;
      float bb = b2s[c];
#pragma unroll
      for (int r = 0; r < 4; ++r) {
        float x = acc[nt][r] + bb;
        acc[nt][r] = x;
        s[r] += x; q[r] += x * x;
      }
    }
#pragma unroll
    for (int m = 8; m >= 1; m >>= 1)
#pragma unroll
      for (int r = 0; r < 4; ++r) { s[r] += __shfl_xor(s[r], m); q[r] += __shfl_xor(q[r], m); }
    if (l15 == 0)
#pragma unroll
      for (int r = 0; r < 4; ++r) { red[w][4 * lg + r][0] = s[r]; red[w][4 * lg + r][1] = q[r]; }
    __syncthreads();
    float mean[4], rs[4];
#pragma unroll
    for (int r = 0; r < 4; ++r) {
      int p = 4 * lg + r;
      float S = red[0][p][0] + red[1][p][0] + red[2][p][0] + red[3][p][0];
      float Q = red[0][p][1] + red[1][p][1] + red[2][p][1] + red[3][p][1];
      mean[r] = S * (1.0f / 512.0f);
      float var = Q * (1.0f / 512.0f) - mean[r] * mean[r];
      rs[r] = rsqrtf(var + EPSV);
    }
#pragma unroll
    for (int nt = 0; nt < 8; ++nt) {
      int c = w * 128 + nt * 16 + l15;
      float gg = g2s[c], bb = be2s[c];
#pragma unroll
      for (int r = 0; r < 4; ++r) {
        int p = 4 * lg + r;
        float v = (acc[nt][r] - mean[r]) * rs[r] * gg + bb;
        v = v > 0.f ? v : 0.f;
        *(ushort_t*)((char*)h2 + ((p * 1024 + c * 2) ^ ((p & 7) << 4))) = f2bf(v);
      }
    }
  }
  __syncthreads();

  // ----- GEMM3: logits[16][64] = h2 @ W3^T ; wave w owns cols [16w,16w+16) -----
  {
    f32x4 a3 = (f32x4){0.f, 0.f, 0.f, 0.f};
#pragma unroll
    for (int ks = 0; ks < 16; ++ks) {
      bf16x8 af = *(const bf16x8*)((char*)h2 + ((l15 * 1024 + ks * 64 + lg * 16) ^ ((l15 & 7) << 4)));
      bf16x8 bfr = *(const bf16x8*)(W3b + (size_t)(w * 16 + l15) * 512 + ks * 32 + lg * 8);
      a3 = __builtin_amdgcn_mfma_f32_16x16x32_bf16(af, bfr, a3, 0, 0, 0);
    }
    int c = w * 16 + l15;
    float bb = b3s[c];
#pragma unroll
    for (int r = 0; r < 4; ++r) lg32[4 * lg + r][c] = a3[r] + bb;
  }
  __syncthreads();

  // ----- softmax over 64 logits -> sb2 (bf16, swizzled) -----
  {
    int r = t >> 4, j = t & 15;
    float v[4];
    float m = -1e30f;
#pragma unroll
    for (int mq = 0; mq < 4; ++mq) { v[mq] = lg32[r][mq * 16 + j]; m = fmaxf(m, v[mq]); }
#pragma unroll
    for (int mk = 8; mk >= 1; mk >>= 1) m = fmaxf(m, __shfl_xor(m, mk));
    float ssum = 0.f;
#pragma unroll
    for (int mq = 0; mq < 4; ++mq) { v[mq] = expf(v[mq] - m); ssum += v[mq]; }
#pragma unroll
    for (int mk = 8; mk >= 1; mk >>= 1) ssum += __shfl_xor(ssum, mk);
    float inv = 1.f / ssum;
#pragma unroll
    for (int mq = 0; mq < 4; ++mq) {
      int c = mq * 16 + j;
      *(ushort_t*)((char*)sb2 + ((r * 128 + c * 2) ^ ((r & 7) << 4))) = f2bf(v[mq] * inv);
    }
  }
  __syncthreads();

  // ----- GEMM4: sp[16][512] = soft @ Wi1shift^T + bi1 -----
  {
    f32x4 a4[8];
#pragma unroll
    for (int nt = 0; nt < 8; ++nt) a4[nt] = (f32x4){0.f, 0.f, 0.f, 0.f};
#pragma unroll
    for (int ks = 0; ks < 2; ++ks) {
      bf16x8 af = *(const bf16x8*)((char*)sb2 + ((l15 * 128 + ks * 64 + lg * 16) ^ ((l15 & 7) << 4)));
#pragma unroll
      for (int nt = 0; nt < 8; ++nt) {
        int c = w * 128 + nt * 16 + l15;
        bf16x8 bfr = *(const bf16x8*)(Wi1sb + (size_t)c * 64 + ks * 32 + lg * 8);
        a4[nt] = __builtin_amdgcn_mfma_f32_16x16x32_bf16(af, bfr, a4[nt], 0, 0, 0);
      }
    }
#pragma unroll
    for (int nt = 0; nt < 8; ++nt) {
      int c = w * 128 + nt * 16 + l15;
      float bb = bi1s[c];
#pragma unroll
      for (int r = 0; r < 4; ++r)
        sp[(size_t)(b0 + 4 * lg + r) * 512 + c] = a4[nt][r] + bb;
    }
  }
}

// ---------------- big fused kernel: h1 -> GEMM1(relu,bi2) -> GEMM2 -> softmax-gather ----------------
__global__ __launch_bounds__(256) void big_kernel(
    const float* __restrict__ a_bits, const float* __restrict__ sp,
    const float* __restrict__ Wi1posT,
    const ushort_t* __restrict__ Wi2b, const ushort_t* __restrict__ Wi3b,
    const float* __restrict__ bi2, const float* __restrict__ bi3,
    float* __restrict__ out) {
  __shared__ __align__(16) ushort_t As[64 * 32];    // h1 k-chunk  [p][i] swizzled, 4KB
  __shared__ __align__(16) ushort_t Bs[256 * 32];   // Wi2 chunk   [c][i] swizzled, 16KB
  __shared__ __align__(16) ushort_t H2s[64 * 256];  // h2 half     [p][c] swizzled, 32KB
  __shared__ float spb[512];
  __shared__ float bi2s[512];
  __shared__ float ab[64];
  __shared__ float bi3s[64];

  int b = blockIdx.x, t = threadIdx.x;
  int w = t >> 6, l = t & 63, lg = l >> 4, l15 = l & 15;

  spb[t] = sp[b * 512 + t]; spb[t + 256] = sp[b * 512 + t + 256];
  bi2s[t] = bi2[t]; bi2s[t + 256] = bi2[t + 256];
  if (t < 64) { ab[t] = a_bits[b * 64 + t]; bi3s[t] = bi3[t]; }
  __syncthreads();

  f32x4 lacc[4];
#pragma unroll
  for (int n = 0; n < 4; ++n) lacc[n] = (f32x4){0.f, 0.f, 0.f, 0.f};

  int pA = t >> 2, xA = t & 3;
  int icA = xA ^ ((pA >> 1) & 3);
  const float* wi1row = Wi1posT + pA * 512 + icA * 8;

  for (int half = 0; half < 2; ++half) {
    int nh0 = half * 256;
    f32x4 acc[4][4];
#pragma unroll
    for (int mt = 0; mt < 4; ++mt)
#pragma unroll
      for (int nt = 0; nt < 4; ++nt) acc[mt][nt] = (f32x4){0.f, 0.f, 0.f, 0.f};

    for (int ks = 0; ks < 16; ++ks) {
      int i0 = ks * 32;
      {
        const float* spp = spb + i0 + icA * 8;
        const float* wp = wi1row + i0;
        float v[8];
#pragma unroll
        for (int j = 0; j < 8; ++j) {
          float x = spp[j] + wp[j];
          v[j] = x > 0.f ? x : 0.f;
        }
        uint4 pk;
        pk.x = (unsigned)f2bf(v[0]) | ((unsigned)f2bf(v[1]) << 16);
        pk.y = (unsigned)f2bf(v[2]) | ((unsigned)f2bf(v[3]) << 16);
        pk.z = (unsigned)f2bf(v[4]) | ((unsigned)f2bf(v[5]) << 16);
        pk.w = (unsigned)f2bf(v[6]) | ((unsigned)f2bf(v[7]) << 16);
        ((uint4*)As)[t] = pk;
      }
      {
        uint4 bq[4];
#pragma unroll
        for (int q = 0; q < 4; ++q) {
          int n = q * 256 + t;
          int c = n >> 2, xg = n & 3;
          int ic = xg ^ ((c >> 1) & 3);
          bq[q] = *(const uint4*)(Wi2b + (size_t)(nh0 + c) * 512 + i0 + ic * 8);
        }
#pragma unroll
        for (int q = 0; q < 4; ++q) ((uint4*)Bs)[q * 256 + t] = bq[q];
      }
      __syncthreads();
      bf16x8 af[4], bfr[4];
#pragma unroll
      for (int mt = 0; mt < 4; ++mt) {
        int p = mt * 16 + l15;
        int gr = p * 4 + (lg ^ ((p >> 1) & 3));
        af[mt] = ((const bf16x8*)As)[gr];
      }
#pragma unroll
      for (int nt = 0; nt < 4; ++nt) {
        int c = w * 64 + nt * 16 + l15;
        int gr = c * 4 + (lg ^ ((c >> 1) & 3));
        bfr[nt] = ((const bf16x8*)Bs)[gr];
      }
#pragma unroll
      for (int mt = 0; mt < 4; ++mt)
#pragma unroll
        for (int nt = 0; nt < 4; ++nt)
          acc[mt][nt] = __builtin_amdgcn_mfma_f32_16x16x32_bf16(af[mt], bfr[nt], acc[mt][nt], 0, 0, 0);
      __syncthreads();
    }
#pragma unroll
    for (int mt = 0; mt < 4; ++mt) {
#pragma unroll
      for (int nt = 0; nt < 4; ++nt) {
        int c = w * 64 + nt * 16 + l15;
        float bi = bi2s[nh0 + c];
#pragma unroll
        for (int r = 0; r < 4; ++r) {
          int p = mt * 16 + 4 * lg + r;
          float v = acc[mt][nt][r] + bi;
          v = v > 0.f ? v : 0.f;
          H2s[p * 256 + (((c >> 3) ^ (p & 7)) * 8) + (c & 7)] = f2bf(v);
        }
      }
    }
    __syncthreads();
    {
      int p2 = 16 * w + l15;
#pragma unroll
      for (int ks2 = 0; ks2 < 8; ++ks2) {
        int gA = (ks2 * 4 + lg) ^ (p2 & 7);
        bf16x8 a2 = *((const bf16x8*)(H2s + p2 * 256 + gA * 8));
        int k2a = nh0 + ks2 * 32 + lg * 8;
#pragma unroll
        for (int nt2 = 0; nt2 < 4; ++nt2) {
          int j2 = nt2 * 16 + l15;
          bf16x8 b2v = *((const bf16x8*)(Wi3b + (size_t)j2 * 512 + k2a));
          lacc[nt2] = __builtin_amdgcn_mfma_f32_16x16x32_bf16(a2, b2v, lacc[nt2], 0, 0, 0);
        }
      }
    }
    __syncthreads();
  }

#pragma unroll
  for (int r = 0; r < 4; ++r) {
    float v[4];
    float m = -1e30f;
#pragma unroll
    for (int nt2 = 0; nt2 < 4; ++nt2) {
      v[nt2] = lacc[nt2][r] + bi3s[nt2 * 16 + l15];
      m = fmaxf(m, v[nt2]);
    }
#pragma unroll
    for (int mm = 8; mm >= 1; mm >>= 1) m = fmaxf(m, __shfl_xor(m, mm));
    float s = 0.f, g = 0.f;
#pragma unroll
    for (int nt2 = 0; nt2 < 4; ++nt2) {
      float e = expf(v[nt2] - m);
      s += e;
      g += e * ab[nt2 * 16 + l15];
    }
#pragma unroll
    for (int mm = 8; mm >= 1; mm >>= 1) { s += __shfl_xor(s, mm); g += __shfl_xor(g, mm); }
    if (l15 == 0) out[b * 64 + 16 * w + 4 * lg + r] = g / s;
  }
}

extern "C" void kernel_launch(void* const* d_in, const int* in_sizes, int n_in,
                              void* d_out, int out_size, void* d_ws, size_t ws_size,
                              hipStream_t stream) {
  const float* a_bits     = (const float*)d_in[0];
  const float* shift_bits = (const float*)d_in[1];
  const float* W1  = (const float*)d_in[2];
  const float* b1  = (const float*)d_in[3];
  const float* g1  = (const float*)d_in[4];
  const float* be1 = (const float*)d_in[5];
  const float* W2  = (const float*)d_in[6];
  const float* b2  = (const float*)d_in[7];
  const float* g2  = (const float*)d_in[8];
  const float* be2 = (const float*)d_in[9];
  const float* W3  = (const float*)d_in[10];
  const float* b3  = (const float*)d_in[11];
  const float* Wi1 = (const float*)d_in[12];
  const float* bi1 = (const float*)d_in[13];
  const float* Wi2 = (const float*)d_in[14];
  const float* bi2 = (const float*)d_in[15];
  const float* Wi3 = (const float*)d_in[16];
  const float* bi3 = (const float*)d_in[17];
  float* out = (float*)d_out;

  // ws layout: sp fp32 [B][512] (8MB) | Wi2b (512KB) | Wi3b (64KB) | Wi1posT (128KB)
  //            | W2b (512KB) | W1b (64KB) | W3b (64KB) | Wi1sb (64KB)  => ~9.4MB
  float* sp = (float*)d_ws;
  ushort_t* Wi2b = (ushort_t*)((char*)d_ws + (size_t)B_N * HID * 4);
  ushort_t* Wi3b = Wi2b + 512 * 512;
  float* Wi1posT = (float*)(Wi3b + 64 * 512);
  ushort_t* W2b = (ushort_t*)(Wi1posT + 64 * 512);
  ushort_t* W1b = W2b + 512 * 512;
  ushort_t* W3b = W1b + 512 * 64;
  ushort_t* Wi1sb = W3b + 64 * 512;

  prep_kernel<<<1024, 256, 0, stream>>>(Wi2, Wi3, Wi1, W1, W2, W3,
                                        Wi2b, Wi3b, Wi1posT, W1b, W2b, W3b, Wi1sb);
  shift2_kernel<<<B_N / BT, 256, 0, stream>>>(shift_bits, W1b, b1, g1, be1,
                                              W2b, b2, g2, be2, W3b, b3, Wi1sb, bi1, sp);
  big_kernel<<<B_N, 256, 0, stream>>>(a_bits, sp, Wi1posT, Wi2b, Wi3b, bi2, bi3, out);
}